// Round 1
// baseline (1123.184 us; speedup 1.0000x reference)
//
#include <hip/hip_runtime.h>
#include <math.h>

#define NN 30000
#define EE 480000
#define FIN 100
#define HCH 256     // heads*hid
#define NCLS 47
#define HC2 188     // heads*ncls

// ---------------- static device workspace (~94 MB) ----------------
__device__ float g_H[(size_t)NN * HCH];   // GEMM output / attention features
__device__ float g_A[(size_t)NN * HCH];   // feature buffer
__device__ float g_B[(size_t)NN * HCH];   // feature buffer
__device__ float g_als[NN * 4];
__device__ float g_ald[NN * 4];
__device__ int   g_rowptr[NN + 1];
__device__ int   g_counts[NN];
__device__ int   g_eids[EE];
__device__ float g_stat[512];             // per-col sum / sumsq

// ---------------- helpers ----------------
__device__ __forceinline__ float wmax(float v) {
#pragma unroll
  for (int o = 32; o > 0; o >>= 1) v = fmaxf(v, __shfl_xor(v, o, 64));
  return v;
}
__device__ __forceinline__ float wsum(float v) {
#pragma unroll
  for (int o = 32; o > 0; o >>= 1) v += __shfl_xor(v, o, 64);
  return v;
}
__device__ __forceinline__ float lrelu(float x) { return x > 0.f ? x : 0.2f * x; }

// ---------------- CSR build ----------------
__global__ void zero_counts_kernel() {
  int i = blockIdx.x * blockDim.x + threadIdx.x;
  if (i < NN) g_counts[i] = 0;
}
__global__ void count_kernel(const int* __restrict__ dst) {
  int e = blockIdx.x * blockDim.x + threadIdx.x;
  if (e < EE) atomicAdd(&g_counts[dst[e]], 1);
}
__global__ void scan_kernel() {
  __shared__ int sh[1024];
  int t = threadIdx.x;
  const int chunk = (NN + 1023) / 1024;
  int start = t * chunk, end = min(start + chunk, NN);
  int local = 0;
  for (int i = start; i < end; i++) local += g_counts[i];
  sh[t] = local;
  __syncthreads();
  for (int off = 1; off < 1024; off <<= 1) {
    int x = (t >= off) ? sh[t - off] : 0;
    __syncthreads();
    sh[t] += x;
    __syncthreads();
  }
  int run = sh[t] - local;  // exclusive prefix for this thread's chunk
  for (int i = start; i < end; i++) {
    g_rowptr[i] = run;
    run += g_counts[i];
    g_counts[i] = 0;  // reset for scatter cursor
  }
  if (t == 0) g_rowptr[NN] = EE;
}
__global__ void scatter_kernel(const int* __restrict__ dst) {
  int e = blockIdx.x * blockDim.x + threadIdx.x;
  if (e < EE) {
    int d = dst[e];
    int pos = g_rowptr[d] + atomicAdd(&g_counts[d], 1);
    g_eids[pos] = e;
  }
}

// ---------------- GEMM: out[nrows,M] (+)= A[nrows,K] @ W[K,M] (+bias) ----------------
__global__ __launch_bounds__(256) void gemm_kernel(
    const float* __restrict__ A, const float* __restrict__ W, float* __restrict__ out,
    int nrows, int K, int M, const float* __restrict__ bias, int accflag) {
  __shared__ __align__(16) float As[16 * 64];  // [kk][m]
  __shared__ __align__(16) float Bs[16 * 64];  // [kk][n]
  int t = threadIdx.x;
  int row0 = blockIdx.y * 64, col0 = blockIdx.x * 64;
  int tm = (t >> 4) << 2, tn = (t & 15) << 2;
  float acc[4][4] = {};
  for (int k0 = 0; k0 < K; k0 += 16) {
#pragma unroll
    for (int u = 0; u < 4; u++) {
      int i = t * 4 + u, m = i >> 4, kk = i & 15;
      int r = row0 + m, k = k0 + kk;
      As[kk * 64 + m] = (r < nrows && k < K) ? A[(size_t)r * K + k] : 0.f;
    }
#pragma unroll
    for (int u = 0; u < 4; u++) {
      int i = t * 4 + u, kk = i >> 6, n = i & 63;
      int k = k0 + kk, c = col0 + n;
      Bs[kk * 64 + n] = (k < K && c < M) ? W[(size_t)k * M + c] : 0.f;
    }
    __syncthreads();
#pragma unroll
    for (int kk = 0; kk < 16; kk++) {
      float4 a4 = *(const float4*)&As[kk * 64 + tm];
      float4 b4 = *(const float4*)&Bs[kk * 64 + tn];
      float a[4] = {a4.x, a4.y, a4.z, a4.w};
      float b[4] = {b4.x, b4.y, b4.z, b4.w};
#pragma unroll
      for (int i = 0; i < 4; i++)
#pragma unroll
        for (int j = 0; j < 4; j++) acc[i][j] += a[i] * b[j];
    }
    __syncthreads();
  }
#pragma unroll
  for (int i = 0; i < 4; i++) {
    int r = row0 + tm + i;
    if (r >= nrows) continue;
#pragma unroll
    for (int j = 0; j < 4; j++) {
      int c = col0 + tn + j;
      if (c >= M) continue;
      float v = acc[i][j];
      if (bias) v += bias[c];
      if (accflag) v += out[(size_t)r * M + c];
      out[(size_t)r * M + c] = v;
    }
  }
}

// ---------------- attention logits per node: al_s/al_d [N,4] ----------------
__global__ void al_kernel(const float* __restrict__ H, const float* __restrict__ a_s,
                          const float* __restrict__ a_d, int C) {
  int wid = threadIdx.x >> 6, lane = threadIdx.x & 63;
  int n = blockIdx.x * 4 + wid;
  if (n >= NN) return;
  int HCl = 4 * C;
  float s0 = 0, s1 = 0, s2 = 0, s3 = 0, d0 = 0, d1 = 0, d2 = 0, d3 = 0;
  if (lane < C) {
    float h0 = H[(size_t)n * HCl + 0 * C + lane];
    float h1 = H[(size_t)n * HCl + 1 * C + lane];
    float h2 = H[(size_t)n * HCl + 2 * C + lane];
    float h3 = H[(size_t)n * HCl + 3 * C + lane];
    s0 = h0 * a_s[0 * C + lane]; s1 = h1 * a_s[1 * C + lane];
    s2 = h2 * a_s[2 * C + lane]; s3 = h3 * a_s[3 * C + lane];
    d0 = h0 * a_d[0 * C + lane]; d1 = h1 * a_d[1 * C + lane];
    d2 = h2 * a_d[2 * C + lane]; d3 = h3 * a_d[3 * C + lane];
  }
  s0 = wsum(s0); s1 = wsum(s1); s2 = wsum(s2); s3 = wsum(s3);
  d0 = wsum(d0); d1 = wsum(d1); d2 = wsum(d2); d3 = wsum(d3);
  if (lane == 0) {
    g_als[n * 4 + 0] = s0; g_als[n * 4 + 1] = s1; g_als[n * 4 + 2] = s2; g_als[n * 4 + 3] = s3;
    g_ald[n * 4 + 0] = d0; g_ald[n * 4 + 1] = d1; g_ald[n * 4 + 2] = d2; g_ald[n * 4 + 3] = d3;
  }
}

// ---------------- fused per-dst softmax + aggregate (C=64, concat) ----------------
__global__ __launch_bounds__(64) void attn_kernel(const float* __restrict__ H,
                                                  const int* __restrict__ src,
                                                  const float* __restrict__ bias,
                                                  float* __restrict__ out) {
  __shared__ __align__(16) float p_sh[64 * 4];
  __shared__ int s_sh[64];
  int n = blockIdx.x, lane = threadIdx.x;
  int rs = g_rowptr[n], deg = g_rowptr[n + 1] - rs;
  float4 ald = *(const float4*)(g_ald + n * 4);
  float m0 = -INFINITY, m1 = -INFINITY, m2 = -INFINITY, m3 = -INFINITY;
  for (int j = lane; j < deg; j += 64) {
    int e = g_eids[rs + j];
    int s = src[e];
    float4 av = *(const float4*)(g_als + s * 4);
    m0 = fmaxf(m0, lrelu(av.x + ald.x));
    m1 = fmaxf(m1, lrelu(av.y + ald.y));
    m2 = fmaxf(m2, lrelu(av.z + ald.z));
    m3 = fmaxf(m3, lrelu(av.w + ald.w));
  }
  m0 = wmax(m0); m1 = wmax(m1); m2 = wmax(m2); m3 = wmax(m3);
  float den0 = 0, den1 = 0, den2 = 0, den3 = 0;
  float a0 = 0, a1 = 0, a2 = 0, a3 = 0;
  for (int base = 0; base < deg; base += 64) {
    int j = base + lane;
    float p0 = 0, p1 = 0, p2 = 0, p3 = 0;
    int s = 0;
    if (j < deg) {
      int e = g_eids[rs + j];
      s = src[e];
      float4 av = *(const float4*)(g_als + s * 4);
      p0 = __expf(lrelu(av.x + ald.x) - m0); den0 += p0;
      p1 = __expf(lrelu(av.y + ald.y) - m1); den1 += p1;
      p2 = __expf(lrelu(av.z + ald.z) - m2); den2 += p2;
      p3 = __expf(lrelu(av.w + ald.w) - m3); den3 += p3;
    }
    p_sh[lane * 4 + 0] = p0; p_sh[lane * 4 + 1] = p1;
    p_sh[lane * 4 + 2] = p2; p_sh[lane * 4 + 3] = p3;
    s_sh[lane] = s;
    __syncthreads();
    int cnt = min(64, deg - base);
    for (int jj = 0; jj < cnt; jj++) {
      int ss = s_sh[jj];
      float4 pv = *(const float4*)&p_sh[jj * 4];
      const float* hr = H + (size_t)ss * 256;
      a0 += pv.x * hr[lane];
      a1 += pv.y * hr[64 + lane];
      a2 += pv.z * hr[128 + lane];
      a3 += pv.w * hr[192 + lane];
    }
    __syncthreads();
  }
  den0 = wsum(den0); den1 = wsum(den1); den2 = wsum(den2); den3 = wsum(den3);
  out[(size_t)n * 256 + lane]       = a0 / (den0 + 1e-16f) + bias[lane];
  out[(size_t)n * 256 + 64 + lane]  = a1 / (den1 + 1e-16f) + bias[64 + lane];
  out[(size_t)n * 256 + 128 + lane] = a2 / (den2 + 1e-16f) + bias[128 + lane];
  out[(size_t)n * 256 + 192 + lane] = a3 / (den3 + 1e-16f) + bias[192 + lane];
}

// ---------------- fused per-dst softmax + aggregate (C=47, mean over heads) ----------------
__global__ __launch_bounds__(64) void attn2_kernel(const float* __restrict__ H,
                                                   const int* __restrict__ src,
                                                   const float* __restrict__ bias,
                                                   float* __restrict__ out) {
  __shared__ __align__(16) float p_sh[64 * 4];
  __shared__ int s_sh[64];
  int n = blockIdx.x, lane = threadIdx.x;
  int rs = g_rowptr[n], deg = g_rowptr[n + 1] - rs;
  float4 ald = *(const float4*)(g_ald + n * 4);
  float m0 = -INFINITY, m1 = -INFINITY, m2 = -INFINITY, m3 = -INFINITY;
  for (int j = lane; j < deg; j += 64) {
    int e = g_eids[rs + j];
    int s = src[e];
    float4 av = *(const float4*)(g_als + s * 4);
    m0 = fmaxf(m0, lrelu(av.x + ald.x));
    m1 = fmaxf(m1, lrelu(av.y + ald.y));
    m2 = fmaxf(m2, lrelu(av.z + ald.z));
    m3 = fmaxf(m3, lrelu(av.w + ald.w));
  }
  m0 = wmax(m0); m1 = wmax(m1); m2 = wmax(m2); m3 = wmax(m3);
  float den0 = 0, den1 = 0, den2 = 0, den3 = 0;
  float a0 = 0, a1 = 0, a2 = 0, a3 = 0;
  for (int base = 0; base < deg; base += 64) {
    int j = base + lane;
    float p0 = 0, p1 = 0, p2 = 0, p3 = 0;
    int s = 0;
    if (j < deg) {
      int e = g_eids[rs + j];
      s = src[e];
      float4 av = *(const float4*)(g_als + s * 4);
      p0 = __expf(lrelu(av.x + ald.x) - m0); den0 += p0;
      p1 = __expf(lrelu(av.y + ald.y) - m1); den1 += p1;
      p2 = __expf(lrelu(av.z + ald.z) - m2); den2 += p2;
      p3 = __expf(lrelu(av.w + ald.w) - m3); den3 += p3;
    }
    p_sh[lane * 4 + 0] = p0; p_sh[lane * 4 + 1] = p1;
    p_sh[lane * 4 + 2] = p2; p_sh[lane * 4 + 3] = p3;
    s_sh[lane] = s;
    __syncthreads();
    int cnt = min(64, deg - base);
    for (int jj = 0; jj < cnt; jj++) {
      int ss = s_sh[jj];
      float4 pv = *(const float4*)&p_sh[jj * 4];
      if (lane < NCLS) {
        const float* hr = H + (size_t)ss * HC2;
        a0 += pv.x * hr[0 * NCLS + lane];
        a1 += pv.y * hr[1 * NCLS + lane];
        a2 += pv.z * hr[2 * NCLS + lane];
        a3 += pv.w * hr[3 * NCLS + lane];
      }
    }
    __syncthreads();
  }
  den0 = wsum(den0); den1 = wsum(den1); den2 = wsum(den2); den3 = wsum(den3);
  if (lane < NCLS) {
    float v = 0.25f * (a0 / (den0 + 1e-16f) + a1 / (den1 + 1e-16f) +
                       a2 / (den2 + 1e-16f) + a3 / (den3 + 1e-16f));
    out[(size_t)n * NCLS + lane] = v + bias[lane];
  }
}

// ---------------- BatchNorm ----------------
__global__ void zero_stat_kernel() {
  int i = blockIdx.x * blockDim.x + threadIdx.x;
  if (i < 512) g_stat[i] = 0.f;
}
__global__ void bn_stats_kernel(const float* __restrict__ X) {
  int c = threadIdx.x;  // 256 cols
  int rows = (NN + gridDim.x - 1) / gridDim.x;
  int r0 = blockIdx.x * rows, r1 = min(r0 + rows, NN);
  float s = 0, q = 0;
  for (int r = r0; r < r1; r++) {
    float v = X[(size_t)r * 256 + c];
    s += v;
    q += v * v;
  }
  atomicAdd(&g_stat[c], s);
  atomicAdd(&g_stat[256 + c], q);
}
__global__ void bn_norm_kernel(float* __restrict__ X, const float* __restrict__ gamma,
                               const float* __restrict__ beta) {
  int i = blockIdx.x * blockDim.x + threadIdx.x;
  if (i >= NN * 256) return;
  int c = i & 255;
  float mu = g_stat[c] * (1.f / NN);
  float var = g_stat[256 + c] * (1.f / NN) - mu * mu;
  float v = (X[i] - mu) * rsqrtf(var + 1e-5f) * gamma[c] + beta[c];
  X[i] = v > 0.f ? v : (__expf(v) - 1.f);  // ELU
}

// ---------------- log_softmax over 47 classes ----------------
__global__ void logsm_kernel(const float* __restrict__ X, float* __restrict__ out) {
  int wid = threadIdx.x >> 6, lane = threadIdx.x & 63;
  int n = blockIdx.x * 4 + wid;
  if (n >= NN) return;
  float v = (lane < NCLS) ? X[(size_t)n * NCLS + lane] : -INFINITY;
  float m = wmax(v);
  float ex = (lane < NCLS) ? __expf(v - m) : 0.f;
  float s = wsum(ex);
  if (lane < NCLS) out[(size_t)n * NCLS + lane] = v - m - logf(s);
}

// ---------------- launch ----------------
extern "C" void kernel_launch(void* const* d_in, const int* in_sizes, int n_in,
                              void* d_out, int out_size, void* d_ws, size_t ws_size,
                              hipStream_t stream) {
  const float* x = (const float*)d_in[0];
  const int* ei = (const int*)d_in[1];
  const int* src = ei;
  const int* dst = ei + EE;
  const float* w0 = (const float*)d_in[2];
  const float* as0 = (const float*)d_in[3];
  const float* ad0 = (const float*)d_in[4];
  const float* b0 = (const float*)d_in[5];
  const float* sw0 = (const float*)d_in[6];
  const float* sb0 = (const float*)d_in[7];
  const float* gm0 = (const float*)d_in[8];
  const float* be0 = (const float*)d_in[9];
  const float* w1 = (const float*)d_in[10];
  const float* as1 = (const float*)d_in[11];
  const float* ad1 = (const float*)d_in[12];
  const float* b1 = (const float*)d_in[13];
  const float* sw1 = (const float*)d_in[14];
  const float* sb1 = (const float*)d_in[15];
  const float* gm1 = (const float*)d_in[16];
  const float* be1 = (const float*)d_in[17];
  const float* w2 = (const float*)d_in[18];
  const float* as2 = (const float*)d_in[19];
  const float* ad2 = (const float*)d_in[20];
  const float* b2 = (const float*)d_in[21];
  const float* sw2 = (const float*)d_in[22];
  const float* sb2 = (const float*)d_in[23];
  float* out = (float*)d_out;

  float *H, *A, *B;
  hipGetSymbolAddress((void**)&H, HIP_SYMBOL(g_H));
  hipGetSymbolAddress((void**)&A, HIP_SYMBOL(g_A));
  hipGetSymbolAddress((void**)&B, HIP_SYMBOL(g_B));

  // CSR by destination (edge_index constant across layers)
  zero_counts_kernel<<<(NN + 255) / 256, 256, 0, stream>>>();
  count_kernel<<<(EE + 255) / 256, 256, 0, stream>>>(dst);
  scan_kernel<<<1, 1024, 0, stream>>>();
  scatter_kernel<<<(EE + 255) / 256, 256, 0, stream>>>(dst);

  const int gy = (NN + 63) / 64;  // 469

  // ---- layer 0 ----
  gemm_kernel<<<dim3(4, gy), 256, 0, stream>>>(x, w0, H, NN, FIN, 256, nullptr, 0);
  al_kernel<<<(NN + 3) / 4, 256, 0, stream>>>(H, as0, ad0, 64);
  attn_kernel<<<NN, 64, 0, stream>>>(H, src, b0, B);
  gemm_kernel<<<dim3(4, gy), 256, 0, stream>>>(x, sw0, B, NN, FIN, 256, sb0, 1);
  zero_stat_kernel<<<2, 256, 0, stream>>>();
  bn_stats_kernel<<<240, 256, 0, stream>>>(B);
  bn_norm_kernel<<<(NN * 256 + 255) / 256, 256, 0, stream>>>(B, gm0, be0);

  // ---- layer 1 ----
  gemm_kernel<<<dim3(4, gy), 256, 0, stream>>>(B, w1, H, NN, 256, 256, nullptr, 0);
  al_kernel<<<(NN + 3) / 4, 256, 0, stream>>>(H, as1, ad1, 64);
  attn_kernel<<<NN, 64, 0, stream>>>(H, src, b1, A);
  gemm_kernel<<<dim3(4, gy), 256, 0, stream>>>(B, sw1, A, NN, 256, 256, sb1, 1);
  zero_stat_kernel<<<2, 256, 0, stream>>>();
  bn_stats_kernel<<<240, 256, 0, stream>>>(A);
  bn_norm_kernel<<<(NN * 256 + 255) / 256, 256, 0, stream>>>(A, gm1, be1);

  // ---- layer 2 ----
  gemm_kernel<<<dim3(3, gy), 256, 0, stream>>>(A, w2, H, NN, 256, HC2, nullptr, 0);
  al_kernel<<<(NN + 3) / 4, 256, 0, stream>>>(H, as2, ad2, NCLS);
  attn2_kernel<<<NN, 64, 0, stream>>>(H, src, b2, B);
  gemm_kernel<<<dim3(1, gy), 256, 0, stream>>>(A, sw2, B, NN, 256, NCLS, sb2, 1);
  logsm_kernel<<<(NN + 3) / 4, 256, 0, stream>>>(B, out);
}

// Round 2
// 786.123 us; speedup vs baseline: 1.4288x; 1.4288x over previous
//
#include <hip/hip_runtime.h>
#include <math.h>

#define NN 30000
#define EE 480000
#define FIN 100
#define HCH 256     // heads*hid
#define NCLS 47
#define HC2 188     // heads*ncls

typedef __attribute__((ext_vector_type(8))) short bf16x8;
typedef __attribute__((ext_vector_type(4))) float f32x4;

// ---------------- static device workspace ----------------
__device__ float g_H[(size_t)NN * HCH];   // GEMM output / attention features
__device__ float g_A[(size_t)NN * HCH];   // feature buffer
__device__ float g_B[(size_t)NN * HCH];   // feature buffer
__device__ float g_als[NN * 4];
__device__ float g_ald[NN * 4];
__device__ int   g_rowptr[NN + 1];
__device__ int   g_counts[NN];
__device__ int   g_eids[EE];
__device__ float g_stat[512];             // per-col sum / sumsq
// bf16 staging
__device__ unsigned short g_Xb[(size_t)NN * 128];   // x padded 100->128
__device__ unsigned short g_Fb[(size_t)NN * 256];   // features bf16
__device__ unsigned short g_Wt0[256 * 128];
__device__ unsigned short g_SWt0[256 * 128];
__device__ unsigned short g_Wt1[256 * 256];
__device__ unsigned short g_SWt1[256 * 256];
__device__ unsigned short g_Wt2[HC2 * 256];
__device__ unsigned short g_SWt2[NCLS * 256];

// ---------------- helpers ----------------
__device__ __forceinline__ float wmax(float v) {
#pragma unroll
  for (int o = 32; o > 0; o >>= 1) v = fmaxf(v, __shfl_xor(v, o, 64));
  return v;
}
__device__ __forceinline__ float wsum(float v) {
#pragma unroll
  for (int o = 32; o > 0; o >>= 1) v += __shfl_xor(v, o, 64);
  return v;
}
__device__ __forceinline__ float lrelu(float x) { return x > 0.f ? x : 0.2f * x; }
__device__ __forceinline__ unsigned short f2bf(float f) {
  unsigned int u = __float_as_uint(f);
  unsigned int r = u + 0x7FFF + ((u >> 16) & 1);
  return (unsigned short)(r >> 16);
}

// ---------------- CSR build ----------------
__global__ void zero_counts_kernel() {
  int i = blockIdx.x * blockDim.x + threadIdx.x;
  if (i < NN) g_counts[i] = 0;
}
__global__ void count_kernel(const int* __restrict__ dst) {
  int e = blockIdx.x * blockDim.x + threadIdx.x;
  if (e < EE) atomicAdd(&g_counts[dst[e]], 1);
}
__global__ void scan_kernel() {
  __shared__ int sh[1024];
  int t = threadIdx.x;
  const int chunk = (NN + 1023) / 1024;
  int start = t * chunk, end = min(start + chunk, NN);
  int local = 0;
  for (int i = start; i < end; i++) local += g_counts[i];
  sh[t] = local;
  __syncthreads();
  for (int off = 1; off < 1024; off <<= 1) {
    int x = (t >= off) ? sh[t - off] : 0;
    __syncthreads();
    sh[t] += x;
    __syncthreads();
  }
  int run = sh[t] - local;
  for (int i = start; i < end; i++) {
    g_rowptr[i] = run;
    run += g_counts[i];
    g_counts[i] = 0;
  }
  if (t == 0) g_rowptr[NN] = EE;
}
__global__ void scatter_kernel(const int* __restrict__ dst) {
  int e = blockIdx.x * blockDim.x + threadIdx.x;
  if (e < EE) {
    int d = dst[e];
    int pos = g_rowptr[d] + atomicAdd(&g_counts[d], 1);
    g_eids[pos] = e;
  }
}

// ---------------- bf16 conversion / weight transpose ----------------
__global__ void conv_x_kernel(const float* __restrict__ x) {
  int i = blockIdx.x * blockDim.x + threadIdx.x;
  if (i >= NN * 128) return;
  int r = i >> 7, k = i & 127;
  g_Xb[i] = (k < FIN) ? f2bf(x[r * FIN + k]) : 0;
}
__global__ void conv_feat_kernel(const float* __restrict__ F) {
  int i = blockIdx.x * blockDim.x + threadIdx.x;
  if (i >= NN * 256) return;
  g_Fb[i] = f2bf(F[i]);
}
// W[K][M] fp32 -> Wt[M][Kp] bf16 (zero-padded K)
__global__ void conv_wt_kernel(const float* __restrict__ W, unsigned short* __restrict__ Wt,
                               int K, int Kp, int M) {
  int i = blockIdx.x * blockDim.x + threadIdx.x;
  if (i >= M * Kp) return;
  int m = i / Kp, k = i - m * Kp;
  Wt[i] = (k < K) ? f2bf(W[(size_t)k * M + m]) : 0;
}

// ---------------- MFMA GEMM: out[nrows,M] (+)= A[nrows,Kp] @ Wt[M,Kp]^T ----------------
// A bf16 row-major (Kp mult of 32), Wt bf16 [M][Kp] (transposed weights), out fp32.
#define LDK 40
__global__ __launch_bounds__(256) void mfma_gemm(
    const unsigned short* __restrict__ A, const unsigned short* __restrict__ Wt,
    float* __restrict__ out, int nrows, int Kp, int M,
    const float* __restrict__ bias, int accflag) {
  __shared__ unsigned short As[64][LDK];
  __shared__ unsigned short Ws[64][LDK];
  int t = threadIdx.x;
  int wave = t >> 6, lane = t & 63;
  int row0 = blockIdx.y * 64, col0 = blockIdx.x * 64;
  int lr = t >> 2;            // 0..63
  int lk = (t & 3) * 8;       // 0,8,16,24
  int m16 = lane & 15, q = lane >> 4;

  f32x4 acc[4];
#pragma unroll
  for (int i = 0; i < 4; i++) acc[i] = (f32x4){0.f, 0.f, 0.f, 0.f};

  for (int k0 = 0; k0 < Kp; k0 += 32) {
    uint4 av = {0, 0, 0, 0};
    int r = row0 + lr;
    if (r < nrows) av = *(const uint4*)(A + (size_t)r * Kp + k0 + lk);
    *(uint4*)(&As[lr][lk]) = av;
    uint4 wv = {0, 0, 0, 0};
    int c = col0 + lr;
    if (c < M) wv = *(const uint4*)(Wt + (size_t)c * Kp + k0 + lk);
    *(uint4*)(&Ws[lr][lk]) = wv;
    __syncthreads();
    bf16x8 bfrag = *(const bf16x8*)(&Ws[wave * 16 + m16][q * 8]);
#pragma unroll
    for (int rt = 0; rt < 4; rt++) {
      bf16x8 afrag = *(const bf16x8*)(&As[rt * 16 + m16][q * 8]);
      acc[rt] = __builtin_amdgcn_mfma_f32_16x16x32_bf16(afrag, bfrag, acc[rt], 0, 0, 0);
    }
    __syncthreads();
  }
  int c = col0 + wave * 16 + m16;
  if (c < M) {
    float bv = bias ? bias[c] : 0.f;
#pragma unroll
    for (int rt = 0; rt < 4; rt++) {
#pragma unroll
      for (int reg = 0; reg < 4; reg++) {
        int r = row0 + rt * 16 + q * 4 + reg;
        if (r < nrows) {
          float v = acc[rt][reg] + bv;
          if (accflag) v += out[(size_t)r * M + c];
          out[(size_t)r * M + c] = v;
        }
      }
    }
  }
}

// ---------------- attention logits per node: al_s/al_d [N,4] ----------------
__global__ void al_kernel(const float* __restrict__ H, const float* __restrict__ a_s,
                          const float* __restrict__ a_d, int C) {
  int wid = threadIdx.x >> 6, lane = threadIdx.x & 63;
  int n = blockIdx.x * 4 + wid;
  if (n >= NN) return;
  int HCl = 4 * C;
  float s0 = 0, s1 = 0, s2 = 0, s3 = 0, d0 = 0, d1 = 0, d2 = 0, d3 = 0;
  if (lane < C) {
    float h0 = H[(size_t)n * HCl + 0 * C + lane];
    float h1 = H[(size_t)n * HCl + 1 * C + lane];
    float h2 = H[(size_t)n * HCl + 2 * C + lane];
    float h3 = H[(size_t)n * HCl + 3 * C + lane];
    s0 = h0 * a_s[0 * C + lane]; s1 = h1 * a_s[1 * C + lane];
    s2 = h2 * a_s[2 * C + lane]; s3 = h3 * a_s[3 * C + lane];
    d0 = h0 * a_d[0 * C + lane]; d1 = h1 * a_d[1 * C + lane];
    d2 = h2 * a_d[2 * C + lane]; d3 = h3 * a_d[3 * C + lane];
  }
  s0 = wsum(s0); s1 = wsum(s1); s2 = wsum(s2); s3 = wsum(s3);
  d0 = wsum(d0); d1 = wsum(d1); d2 = wsum(d2); d3 = wsum(d3);
  if (lane == 0) {
    g_als[n * 4 + 0] = s0; g_als[n * 4 + 1] = s1; g_als[n * 4 + 2] = s2; g_als[n * 4 + 3] = s3;
    g_ald[n * 4 + 0] = d0; g_ald[n * 4 + 1] = d1; g_ald[n * 4 + 2] = d2; g_ald[n * 4 + 3] = d3;
  }
}

// ---------------- fused per-dst softmax + aggregate (C=64, concat) ----------------
__global__ __launch_bounds__(64) void attn_kernel(const float* __restrict__ H,
                                                  const int* __restrict__ src,
                                                  const float* __restrict__ bias,
                                                  float* __restrict__ out) {
  __shared__ __align__(16) float p_sh[64 * 4];
  __shared__ int s_sh[64];
  int n = blockIdx.x, lane = threadIdx.x;
  int rs = g_rowptr[n], deg = g_rowptr[n + 1] - rs;
  float4 ald = *(const float4*)(g_ald + n * 4);
  float m0 = -INFINITY, m1 = -INFINITY, m2 = -INFINITY, m3 = -INFINITY;
  for (int j = lane; j < deg; j += 64) {
    int e = g_eids[rs + j];
    int s = src[e];
    float4 av = *(const float4*)(g_als + s * 4);
    m0 = fmaxf(m0, lrelu(av.x + ald.x));
    m1 = fmaxf(m1, lrelu(av.y + ald.y));
    m2 = fmaxf(m2, lrelu(av.z + ald.z));
    m3 = fmaxf(m3, lrelu(av.w + ald.w));
  }
  m0 = wmax(m0); m1 = wmax(m1); m2 = wmax(m2); m3 = wmax(m3);
  float den0 = 0, den1 = 0, den2 = 0, den3 = 0;
  float a0 = 0, a1 = 0, a2 = 0, a3 = 0;
  for (int base = 0; base < deg; base += 64) {
    int j = base + lane;
    float p0 = 0, p1 = 0, p2 = 0, p3 = 0;
    int s = 0;
    if (j < deg) {
      int e = g_eids[rs + j];
      s = src[e];
      float4 av = *(const float4*)(g_als + s * 4);
      p0 = __expf(lrelu(av.x + ald.x) - m0); den0 += p0;
      p1 = __expf(lrelu(av.y + ald.y) - m1); den1 += p1;
      p2 = __expf(lrelu(av.z + ald.z) - m2); den2 += p2;
      p3 = __expf(lrelu(av.w + ald.w) - m3); den3 += p3;
    }
    p_sh[lane * 4 + 0] = p0; p_sh[lane * 4 + 1] = p1;
    p_sh[lane * 4 + 2] = p2; p_sh[lane * 4 + 3] = p3;
    s_sh[lane] = s;
    __syncthreads();
    int cnt = min(64, deg - base);
    for (int jj = 0; jj < cnt; jj++) {
      int ss = s_sh[jj];
      float4 pv = *(const float4*)&p_sh[jj * 4];
      const float* hr = H + (size_t)ss * 256;
      a0 += pv.x * hr[lane];
      a1 += pv.y * hr[64 + lane];
      a2 += pv.z * hr[128 + lane];
      a3 += pv.w * hr[192 + lane];
    }
    __syncthreads();
  }
  den0 = wsum(den0); den1 = wsum(den1); den2 = wsum(den2); den3 = wsum(den3);
  out[(size_t)n * 256 + lane]       = a0 / (den0 + 1e-16f) + bias[lane];
  out[(size_t)n * 256 + 64 + lane]  = a1 / (den1 + 1e-16f) + bias[64 + lane];
  out[(size_t)n * 256 + 128 + lane] = a2 / (den2 + 1e-16f) + bias[128 + lane];
  out[(size_t)n * 256 + 192 + lane] = a3 / (den3 + 1e-16f) + bias[192 + lane];
}

// ---------------- fused per-dst softmax + aggregate (C=47, mean over heads) ----------------
__global__ __launch_bounds__(64) void attn2_kernel(const float* __restrict__ H,
                                                   const int* __restrict__ src,
                                                   const float* __restrict__ bias,
                                                   float* __restrict__ out) {
  __shared__ __align__(16) float p_sh[64 * 4];
  __shared__ int s_sh[64];
  int n = blockIdx.x, lane = threadIdx.x;
  int rs = g_rowptr[n], deg = g_rowptr[n + 1] - rs;
  float4 ald = *(const float4*)(g_ald + n * 4);
  float m0 = -INFINITY, m1 = -INFINITY, m2 = -INFINITY, m3 = -INFINITY;
  for (int j = lane; j < deg; j += 64) {
    int e = g_eids[rs + j];
    int s = src[e];
    float4 av = *(const float4*)(g_als + s * 4);
    m0 = fmaxf(m0, lrelu(av.x + ald.x));
    m1 = fmaxf(m1, lrelu(av.y + ald.y));
    m2 = fmaxf(m2, lrelu(av.z + ald.z));
    m3 = fmaxf(m3, lrelu(av.w + ald.w));
  }
  m0 = wmax(m0); m1 = wmax(m1); m2 = wmax(m2); m3 = wmax(m3);
  float den0 = 0, den1 = 0, den2 = 0, den3 = 0;
  float a0 = 0, a1 = 0, a2 = 0, a3 = 0;
  for (int base = 0; base < deg; base += 64) {
    int j = base + lane;
    float p0 = 0, p1 = 0, p2 = 0, p3 = 0;
    int s = 0;
    if (j < deg) {
      int e = g_eids[rs + j];
      s = src[e];
      float4 av = *(const float4*)(g_als + s * 4);
      p0 = __expf(lrelu(av.x + ald.x) - m0); den0 += p0;
      p1 = __expf(lrelu(av.y + ald.y) - m1); den1 += p1;
      p2 = __expf(lrelu(av.z + ald.z) - m2); den2 += p2;
      p3 = __expf(lrelu(av.w + ald.w) - m3); den3 += p3;
    }
    p_sh[lane * 4 + 0] = p0; p_sh[lane * 4 + 1] = p1;
    p_sh[lane * 4 + 2] = p2; p_sh[lane * 4 + 3] = p3;
    s_sh[lane] = s;
    __syncthreads();
    int cnt = min(64, deg - base);
    for (int jj = 0; jj < cnt; jj++) {
      int ss = s_sh[jj];
      float4 pv = *(const float4*)&p_sh[jj * 4];
      if (lane < NCLS) {
        const float* hr = H + (size_t)ss * HC2;
        a0 += pv.x * hr[0 * NCLS + lane];
        a1 += pv.y * hr[1 * NCLS + lane];
        a2 += pv.z * hr[2 * NCLS + lane];
        a3 += pv.w * hr[3 * NCLS + lane];
      }
    }
    __syncthreads();
  }
  den0 = wsum(den0); den1 = wsum(den1); den2 = wsum(den2); den3 = wsum(den3);
  if (lane < NCLS) {
    float v = 0.25f * (a0 / (den0 + 1e-16f) + a1 / (den1 + 1e-16f) +
                       a2 / (den2 + 1e-16f) + a3 / (den3 + 1e-16f));
    out[(size_t)n * NCLS + lane] = v + bias[lane];
  }
}

// ---------------- BatchNorm ----------------
__global__ void zero_stat_kernel() {
  int i = blockIdx.x * blockDim.x + threadIdx.x;
  if (i < 512) g_stat[i] = 0.f;
}
__global__ void bn_stats_kernel(const float* __restrict__ X) {
  int c = threadIdx.x;  // 256 cols
  int rows = (NN + gridDim.x - 1) / gridDim.x;
  int r0 = blockIdx.x * rows, r1 = min(r0 + rows, NN);
  float s = 0, q = 0;
  for (int r = r0; r < r1; r++) {
    float v = X[(size_t)r * 256 + c];
    s += v;
    q += v * v;
  }
  atomicAdd(&g_stat[c], s);
  atomicAdd(&g_stat[256 + c], q);
}
__global__ void bn_norm_kernel(float* __restrict__ X, const float* __restrict__ gamma,
                               const float* __restrict__ beta) {
  int i = blockIdx.x * blockDim.x + threadIdx.x;
  if (i >= NN * 256) return;
  int c = i & 255;
  float mu = g_stat[c] * (1.f / NN);
  float var = g_stat[256 + c] * (1.f / NN) - mu * mu;
  float v = (X[i] - mu) * rsqrtf(var + 1e-5f) * gamma[c] + beta[c];
  X[i] = v > 0.f ? v : (__expf(v) - 1.f);  // ELU
}

// ---------------- log_softmax over 47 classes ----------------
__global__ void logsm_kernel(const float* __restrict__ X, float* __restrict__ out) {
  int wid = threadIdx.x >> 6, lane = threadIdx.x & 63;
  int n = blockIdx.x * 4 + wid;
  if (n >= NN) return;
  float v = (lane < NCLS) ? X[(size_t)n * NCLS + lane] : -INFINITY;
  float m = wmax(v);
  float ex = (lane < NCLS) ? __expf(v - m) : 0.f;
  float s = wsum(ex);
  if (lane < NCLS) out[(size_t)n * NCLS + lane] = v - m - logf(s);
}

// ---------------- launch ----------------
extern "C" void kernel_launch(void* const* d_in, const int* in_sizes, int n_in,
                              void* d_out, int out_size, void* d_ws, size_t ws_size,
                              hipStream_t stream) {
  const float* x = (const float*)d_in[0];
  const int* ei = (const int*)d_in[1];
  const int* src = ei;
  const int* dst = ei + EE;
  const float* w0 = (const float*)d_in[2];
  const float* as0 = (const float*)d_in[3];
  const float* ad0 = (const float*)d_in[4];
  const float* b0 = (const float*)d_in[5];
  const float* sw0 = (const float*)d_in[6];
  const float* sb0 = (const float*)d_in[7];
  const float* gm0 = (const float*)d_in[8];
  const float* be0 = (const float*)d_in[9];
  const float* w1 = (const float*)d_in[10];
  const float* as1 = (const float*)d_in[11];
  const float* ad1 = (const float*)d_in[12];
  const float* b1 = (const float*)d_in[13];
  const float* sw1 = (const float*)d_in[14];
  const float* sb1 = (const float*)d_in[15];
  const float* gm1 = (const float*)d_in[16];
  const float* be1 = (const float*)d_in[17];
  const float* w2 = (const float*)d_in[18];
  const float* as2 = (const float*)d_in[19];
  const float* ad2 = (const float*)d_in[20];
  const float* b2 = (const float*)d_in[21];
  const float* sw2 = (const float*)d_in[22];
  const float* sb2 = (const float*)d_in[23];
  float* out = (float*)d_out;

  float *H, *A, *B;
  hipGetSymbolAddress((void**)&H, HIP_SYMBOL(g_H));
  hipGetSymbolAddress((void**)&A, HIP_SYMBOL(g_A));
  hipGetSymbolAddress((void**)&B, HIP_SYMBOL(g_B));
  unsigned short *Xb, *Fb, *Wt0, *SWt0, *Wt1, *SWt1, *Wt2, *SWt2;
  hipGetSymbolAddress((void**)&Xb, HIP_SYMBOL(g_Xb));
  hipGetSymbolAddress((void**)&Fb, HIP_SYMBOL(g_Fb));
  hipGetSymbolAddress((void**)&Wt0, HIP_SYMBOL(g_Wt0));
  hipGetSymbolAddress((void**)&SWt0, HIP_SYMBOL(g_SWt0));
  hipGetSymbolAddress((void**)&Wt1, HIP_SYMBOL(g_Wt1));
  hipGetSymbolAddress((void**)&SWt1, HIP_SYMBOL(g_SWt1));
  hipGetSymbolAddress((void**)&Wt2, HIP_SYMBOL(g_Wt2));
  hipGetSymbolAddress((void**)&SWt2, HIP_SYMBOL(g_SWt2));

  // CSR by destination (edge_index constant across layers)
  zero_counts_kernel<<<(NN + 255) / 256, 256, 0, stream>>>();
  count_kernel<<<(EE + 255) / 256, 256, 0, stream>>>(dst);
  scan_kernel<<<1, 1024, 0, stream>>>();
  scatter_kernel<<<(EE + 255) / 256, 256, 0, stream>>>(dst);

  // weight conversions (small)
  conv_wt_kernel<<<(256 * 128 + 255) / 256, 256, 0, stream>>>(w0, Wt0, FIN, 128, 256);
  conv_wt_kernel<<<(256 * 128 + 255) / 256, 256, 0, stream>>>(sw0, SWt0, FIN, 128, 256);
  conv_wt_kernel<<<(256 * 256 + 255) / 256, 256, 0, stream>>>(w1, Wt1, 256, 256, 256);
  conv_wt_kernel<<<(256 * 256 + 255) / 256, 256, 0, stream>>>(sw1, SWt1, 256, 256, 256);
  conv_wt_kernel<<<(HC2 * 256 + 255) / 256, 256, 0, stream>>>(w2, Wt2, 256, 256, HC2);
  conv_wt_kernel<<<(NCLS * 256 + 255) / 256, 256, 0, stream>>>(sw2, SWt2, 256, 256, NCLS);
  conv_x_kernel<<<(NN * 128 + 255) / 256, 256, 0, stream>>>(x);

  const int gy = (NN + 63) / 64;  // 469

  // ---- layer 0 ----
  mfma_gemm<<<dim3(4, gy), 256, 0, stream>>>(Xb, Wt0, H, NN, 128, 256, nullptr, 0);
  al_kernel<<<(NN + 3) / 4, 256, 0, stream>>>(H, as0, ad0, 64);
  attn_kernel<<<NN, 64, 0, stream>>>(H, src, b0, B);
  mfma_gemm<<<dim3(4, gy), 256, 0, stream>>>(Xb, SWt0, B, NN, 128, 256, sb0, 1);
  zero_stat_kernel<<<2, 256, 0, stream>>>();
  bn_stats_kernel<<<240, 256, 0, stream>>>(B);
  bn_norm_kernel<<<(NN * 256 + 255) / 256, 256, 0, stream>>>(B, gm0, be0);

  // ---- layer 1 ----
  conv_feat_kernel<<<(NN * 256 + 255) / 256, 256, 0, stream>>>(B);
  mfma_gemm<<<dim3(4, gy), 256, 0, stream>>>(Fb, Wt1, H, NN, 256, 256, nullptr, 0);
  al_kernel<<<(NN + 3) / 4, 256, 0, stream>>>(H, as1, ad1, 64);
  attn_kernel<<<NN, 64, 0, stream>>>(H, src, b1, A);
  mfma_gemm<<<dim3(4, gy), 256, 0, stream>>>(Fb, SWt1, A, NN, 256, 256, sb1, 1);
  zero_stat_kernel<<<2, 256, 0, stream>>>();
  bn_stats_kernel<<<240, 256, 0, stream>>>(A);
  bn_norm_kernel<<<(NN * 256 + 255) / 256, 256, 0, stream>>>(A, gm1, be1);

  // ---- layer 2 ----
  conv_feat_kernel<<<(NN * 256 + 255) / 256, 256, 0, stream>>>(A);
  mfma_gemm<<<dim3(3, gy), 256, 0, stream>>>(Fb, Wt2, H, NN, 256, HC2, nullptr, 0);
  al_kernel<<<(NN + 3) / 4, 256, 0, stream>>>(H, as2, ad2, NCLS);
  attn2_kernel<<<NN, 64, 0, stream>>>(H, src, b2, B);
  mfma_gemm<<<dim3(1, gy), 256, 0, stream>>>(Fb, SWt2, B, NN, 256, NCLS, sb2, 1);
  logsm_kernel<<<(NN + 3) / 4, 256, 0, stream>>>(B, out);
}

// Round 3
// 642.284 us; speedup vs baseline: 1.7487x; 1.2240x over previous
//
#include <hip/hip_runtime.h>
#include <math.h>

#define NN 30000
#define EE 480000
#define FIN 100
#define NCLS 47
#define HC2 188     // heads*ncls

typedef unsigned short ushortt;
typedef __attribute__((ext_vector_type(8))) short bf16x8;
typedef __attribute__((ext_vector_type(4))) float f32x4;

// ---------------- static device workspace ----------------
__device__ ushortt g_Hb[(size_t)NN * 256];   // attention features h, bf16 (layer2: [N,188])
__device__ float   g_Sf[(size_t)NN * 256];   // skip pre-sum fp32, then pre-BN in place
__device__ ushortt g_Fb[(size_t)NN * 256];   // post-BN features bf16 (next GEMM input)
__device__ ushortt g_Xb[(size_t)NN * 128];   // x padded 100->128, bf16
__device__ ushortt g_Wc0[512 * 128];         // [W0 | SW0]^T bf16
__device__ ushortt g_Wc1[512 * 256];         // [W1 | SW1]^T
__device__ ushortt g_Wc2[235 * 256];         // [W2(188) | SW2(47)]^T
__device__ float g_als[NN * 4];
__device__ float g_ald[NN * 4];
__device__ int   g_rowptr[NN + 1];
__device__ int   g_counts[NN];
__device__ int   g_eids[EE];
__device__ float g_stat[512];                // per-col sum / sumsq

// ---------------- helpers ----------------
__device__ __forceinline__ float wsum(float v) {
#pragma unroll
  for (int o = 32; o > 0; o >>= 1) v += __shfl_xor(v, o, 64);
  return v;
}
__device__ __forceinline__ float lrelu(float x) { return x > 0.f ? x : 0.2f * x; }
__device__ __forceinline__ ushortt f2bf(float f) {
  unsigned int u = __float_as_uint(f);
  unsigned int r = u + 0x7FFF + ((u >> 16) & 1);
  return (ushortt)(r >> 16);
}
__device__ __forceinline__ float bf2f(ushortt u) {
  return __uint_as_float(((unsigned int)u) << 16);
}

// ---------------- CSR build ----------------
__global__ void zero_counts_kernel() {
  int i = blockIdx.x * blockDim.x + threadIdx.x;
  if (i < NN) g_counts[i] = 0;
}
__global__ void count_kernel(const int* __restrict__ dst) {
  int e = blockIdx.x * blockDim.x + threadIdx.x;
  if (e < EE) atomicAdd(&g_counts[dst[e]], 1);
}
__global__ void scan_kernel() {
  __shared__ int sh[1024];
  int t = threadIdx.x;
  const int chunk = (NN + 1023) / 1024;
  int start = t * chunk, end = min(start + chunk, NN);
  int local = 0;
  for (int i = start; i < end; i++) local += g_counts[i];
  sh[t] = local;
  __syncthreads();
  for (int off = 1; off < 1024; off <<= 1) {
    int x = (t >= off) ? sh[t - off] : 0;
    __syncthreads();
    sh[t] += x;
    __syncthreads();
  }
  int run = sh[t] - local;
  for (int i = start; i < end; i++) {
    g_rowptr[i] = run;
    run += g_counts[i];
    g_counts[i] = 0;
  }
  if (t == 0) g_rowptr[NN] = EE;
}
__global__ void scatter_kernel(const int* __restrict__ dst) {
  int e = blockIdx.x * blockDim.x + threadIdx.x;
  if (e < EE) {
    int d = dst[e];
    int pos = g_rowptr[d] + atomicAdd(&g_counts[d], 1);
    g_eids[pos] = e;
  }
}

// ---------------- conversions ----------------
__global__ void conv_x_kernel(const float* __restrict__ x) {
  int i = blockIdx.x * blockDim.x + threadIdx.x;
  if (i >= NN * 128) return;
  int r = i >> 7, k = i & 127;
  g_Xb[i] = (k < FIN) ? f2bf(x[r * FIN + k]) : 0;
}
// all weights -> concatenated transposed bf16 buffers
__global__ void conv_w_kernel(const float* __restrict__ w0, const float* __restrict__ sw0,
                              const float* __restrict__ w1, const float* __restrict__ sw1,
                              const float* __restrict__ w2, const float* __restrict__ sw2) {
  int i = blockIdx.x * blockDim.x + threadIdx.x;
  if (i < 512 * 128) {
    int m = i >> 7, k = i & 127;
    float v = 0.f;
    if (k < FIN) v = (m < 256) ? w0[k * 256 + m] : sw0[k * 256 + (m - 256)];
    g_Wc0[i] = f2bf(v);
    return;
  }
  i -= 512 * 128;
  if (i < 512 * 256) {
    int m = i >> 8, k = i & 255;
    float v = (m < 256) ? w1[k * 256 + m] : sw1[k * 256 + (m - 256)];
    g_Wc1[i] = f2bf(v);
    return;
  }
  i -= 512 * 256;
  if (i < 235 * 256) {
    int m = i >> 8, k = i & 255;
    float v = (m < 188) ? w2[(size_t)k * 188 + m] : sw2[(size_t)k * 47 + (m - 188)];
    g_Wc2[i] = f2bf(v);
  }
}

// ---------------- MFMA GEMM with split epilogue ----------------
// A bf16 [nrows,Kp]; Wt bf16 [M][Kp]; cols < S -> out1 bf16 (no bias);
// cols >= S -> out2 fp32 (+bias2).
__global__ __launch_bounds__(256) void mfma_gemm(
    const ushortt* __restrict__ A, const ushortt* __restrict__ Wt,
    ushortt* __restrict__ out1, float* __restrict__ out2,
    int nrows, int Kp, int M, int S, int ld1, int ld2,
    const float* __restrict__ bias2) {
  __shared__ ushortt As[64][40];
  __shared__ ushortt Ws[64][40];
  int t = threadIdx.x;
  int wave = t >> 6, lane = t & 63;
  int row0 = blockIdx.y * 64, col0 = blockIdx.x * 64;
  int lr = t >> 2;
  int lk = (t & 3) * 8;
  int m16 = lane & 15, q = lane >> 4;

  f32x4 acc[4];
#pragma unroll
  for (int i = 0; i < 4; i++) acc[i] = (f32x4){0.f, 0.f, 0.f, 0.f};

  for (int k0 = 0; k0 < Kp; k0 += 32) {
    uint4 av = {0, 0, 0, 0};
    int r = row0 + lr;
    if (r < nrows) av = *(const uint4*)(A + (size_t)r * Kp + k0 + lk);
    *(uint4*)(&As[lr][lk]) = av;
    uint4 wv = {0, 0, 0, 0};
    int c = col0 + lr;
    if (c < M) wv = *(const uint4*)(Wt + (size_t)c * Kp + k0 + lk);
    *(uint4*)(&Ws[lr][lk]) = wv;
    __syncthreads();
    bf16x8 bfrag = *(const bf16x8*)(&Ws[wave * 16 + m16][q * 8]);
#pragma unroll
    for (int rt = 0; rt < 4; rt++) {
      bf16x8 afrag = *(const bf16x8*)(&As[rt * 16 + m16][q * 8]);
      acc[rt] = __builtin_amdgcn_mfma_f32_16x16x32_bf16(afrag, bfrag, acc[rt], 0, 0, 0);
    }
    __syncthreads();
  }
  int c = col0 + wave * 16 + m16;
  if (c < M) {
#pragma unroll
    for (int rt = 0; rt < 4; rt++) {
#pragma unroll
      for (int reg = 0; reg < 4; reg++) {
        int r = row0 + rt * 16 + q * 4 + reg;
        if (r < nrows) {
          float v = acc[rt][reg];
          if (c < S) out1[(size_t)r * ld1 + c] = f2bf(v);
          else out2[(size_t)r * ld2 + (c - S)] = v + bias2[c - S];
        }
      }
    }
  }
}

// ---------------- attention logits per node: al_s/al_d [N,4] (bf16 input) ----------------
__global__ void al_kernel(const ushortt* __restrict__ Hb, const float* __restrict__ a_s,
                          const float* __restrict__ a_d, int C) {
  int wid = threadIdx.x >> 6, lane = threadIdx.x & 63;
  int n = blockIdx.x * 4 + wid;
  if (n >= NN) return;
  int HCl = 4 * C;
  float s0 = 0, s1 = 0, s2 = 0, s3 = 0, d0 = 0, d1 = 0, d2 = 0, d3 = 0;
  if (lane < C) {
    float h0 = bf2f(Hb[(size_t)n * HCl + 0 * C + lane]);
    float h1 = bf2f(Hb[(size_t)n * HCl + 1 * C + lane]);
    float h2 = bf2f(Hb[(size_t)n * HCl + 2 * C + lane]);
    float h3 = bf2f(Hb[(size_t)n * HCl + 3 * C + lane]);
    s0 = h0 * a_s[0 * C + lane]; s1 = h1 * a_s[1 * C + lane];
    s2 = h2 * a_s[2 * C + lane]; s3 = h3 * a_s[3 * C + lane];
    d0 = h0 * a_d[0 * C + lane]; d1 = h1 * a_d[1 * C + lane];
    d2 = h2 * a_d[2 * C + lane]; d3 = h3 * a_d[3 * C + lane];
  }
  s0 = wsum(s0); s1 = wsum(s1); s2 = wsum(s2); s3 = wsum(s3);
  d0 = wsum(d0); d1 = wsum(d1); d2 = wsum(d2); d3 = wsum(d3);
  if (lane == 0) {
    g_als[n * 4 + 0] = s0; g_als[n * 4 + 1] = s1; g_als[n * 4 + 2] = s2; g_als[n * 4 + 3] = s3;
    g_ald[n * 4 + 0] = d0; g_ald[n * 4 + 1] = d1; g_ald[n * 4 + 2] = d2; g_ald[n * 4 + 3] = d3;
  }
}

// ---------------- fused softmax + aggregate + skip-add, C=64 concat ----------------
// No max-subtraction: logits are lrelu of O(1) sums, exp cannot overflow, and
// softmax is shift-invariant. Output written in place over Sf (pre-BN sum).
__global__ __launch_bounds__(64) void attn_kernel(const ushortt* __restrict__ Hb,
                                                  const int* __restrict__ src,
                                                  const float* __restrict__ bias,
                                                  float* __restrict__ Sf) {
  __shared__ __align__(16) float p_sh[64 * 4];
  __shared__ int s_sh[64];
  int n = blockIdx.x, lane = threadIdx.x;
  int rs = g_rowptr[n], deg = g_rowptr[n + 1] - rs;
  float4 ald = *(const float4*)(g_ald + n * 4);
  int q = lane >> 4;
  float den0 = 0, den1 = 0, den2 = 0, den3 = 0;
  float a0 = 0, a1 = 0, a2 = 0, a3 = 0;
  for (int base = 0; base < deg; base += 64) {
    int j = base + lane;
    float p0 = 0, p1 = 0, p2 = 0, p3 = 0;
    int s = 0;
    if (j < deg) {
      int e = g_eids[rs + j];
      s = src[e];
      float4 av = *(const float4*)(g_als + s * 4);
      p0 = __expf(lrelu(av.x + ald.x)); den0 += p0;
      p1 = __expf(lrelu(av.y + ald.y)); den1 += p1;
      p2 = __expf(lrelu(av.z + ald.z)); den2 += p2;
      p3 = __expf(lrelu(av.w + ald.w)); den3 += p3;
    }
    p_sh[lane * 4 + 0] = p0; p_sh[lane * 4 + 1] = p1;
    p_sh[lane * 4 + 2] = p2; p_sh[lane * 4 + 3] = p3;
    s_sh[lane] = s;
    __syncthreads();
    int cnt = min(64, deg - base);
    for (int jj = 0; jj < cnt; jj++) {
      int ss = s_sh[jj];
      float p = p_sh[jj * 4 + q];
      ushort4 hv = *(const ushort4*)(Hb + (size_t)ss * 256 + 4 * lane);
      a0 += p * bf2f(hv.x);
      a1 += p * bf2f(hv.y);
      a2 += p * bf2f(hv.z);
      a3 += p * bf2f(hv.w);
    }
    __syncthreads();
  }
  den0 = wsum(den0); den1 = wsum(den1); den2 = wsum(den2); den3 = wsum(den3);
  float denq = (q == 0) ? den0 : (q == 1) ? den1 : (q == 2) ? den2 : den3;
  float inv = 1.f / (denq + 1e-16f);
  float4 sv = *(const float4*)(Sf + (size_t)n * 256 + 4 * lane);
  float4 bv = *(const float4*)(bias + 4 * lane);
  float4 o;
  o.x = a0 * inv + bv.x + sv.x;
  o.y = a1 * inv + bv.y + sv.y;
  o.z = a2 * inv + bv.z + sv.z;
  o.w = a3 * inv + bv.w + sv.w;
  *(float4*)(Sf + (size_t)n * 256 + 4 * lane) = o;
}

// ---------------- layer-2: softmax + aggregate, mean over heads, +skip ----------------
__global__ __launch_bounds__(64) void attn2_kernel(const ushortt* __restrict__ Hb,
                                                   const int* __restrict__ src,
                                                   const float* __restrict__ bias,
                                                   float* __restrict__ Sf) {
  __shared__ __align__(16) float p_sh[64 * 4];
  __shared__ int s_sh[64];
  int n = blockIdx.x, lane = threadIdx.x;
  int rs = g_rowptr[n], deg = g_rowptr[n + 1] - rs;
  float4 ald = *(const float4*)(g_ald + n * 4);
  float den0 = 0, den1 = 0, den2 = 0, den3 = 0;
  float a0 = 0, a1 = 0, a2 = 0, a3 = 0;
  for (int base = 0; base < deg; base += 64) {
    int j = base + lane;
    float p0 = 0, p1 = 0, p2 = 0, p3 = 0;
    int s = 0;
    if (j < deg) {
      int e = g_eids[rs + j];
      s = src[e];
      float4 av = *(const float4*)(g_als + s * 4);
      p0 = __expf(lrelu(av.x + ald.x)); den0 += p0;
      p1 = __expf(lrelu(av.y + ald.y)); den1 += p1;
      p2 = __expf(lrelu(av.z + ald.z)); den2 += p2;
      p3 = __expf(lrelu(av.w + ald.w)); den3 += p3;
    }
    p_sh[lane * 4 + 0] = p0; p_sh[lane * 4 + 1] = p1;
    p_sh[lane * 4 + 2] = p2; p_sh[lane * 4 + 3] = p3;
    s_sh[lane] = s;
    __syncthreads();
    int cnt = min(64, deg - base);
    for (int jj = 0; jj < cnt; jj++) {
      int ss = s_sh[jj];
      float4 pv = *(const float4*)&p_sh[jj * 4];
      if (lane < NCLS) {
        const ushortt* hr = Hb + (size_t)ss * HC2;
        a0 += pv.x * bf2f(hr[0 * NCLS + lane]);
        a1 += pv.y * bf2f(hr[1 * NCLS + lane]);
        a2 += pv.z * bf2f(hr[2 * NCLS + lane]);
        a3 += pv.w * bf2f(hr[3 * NCLS + lane]);
      }
    }
    __syncthreads();
  }
  den0 = wsum(den0); den1 = wsum(den1); den2 = wsum(den2); den3 = wsum(den3);
  if (lane < NCLS) {
    float v = 0.25f * (a0 / (den0 + 1e-16f) + a1 / (den1 + 1e-16f) +
                       a2 / (den2 + 1e-16f) + a3 / (den3 + 1e-16f));
    Sf[(size_t)n * NCLS + lane] = v + bias[lane] + Sf[(size_t)n * NCLS + lane];
  }
}

// ---------------- BatchNorm ----------------
__global__ void zero_stat_kernel() {
  int i = blockIdx.x * blockDim.x + threadIdx.x;
  if (i < 512) g_stat[i] = 0.f;
}
__global__ void bn_stats_kernel(const float* __restrict__ X) {
  int c = threadIdx.x;  // 256 cols
  int rows = (NN + gridDim.x - 1) / gridDim.x;
  int r0 = blockIdx.x * rows, r1 = min(r0 + rows, NN);
  float s = 0, q = 0;
  for (int r = r0; r < r1; r++) {
    float v = X[(size_t)r * 256 + c];
    s += v;
    q += v * v;
  }
  atomicAdd(&g_stat[c], s);
  atomicAdd(&g_stat[256 + c], q);
}
// normalize + ELU, write bf16 features for next layer's GEMM
__global__ void bn_norm_kernel(const float* __restrict__ X, const float* __restrict__ gamma,
                               const float* __restrict__ beta) {
  int i = blockIdx.x * blockDim.x + threadIdx.x;
  if (i >= NN * 256) return;
  int c = i & 255;
  float mu = g_stat[c] * (1.f / NN);
  float var = g_stat[256 + c] * (1.f / NN) - mu * mu;
  float v = (X[i] - mu) * rsqrtf(var + 1e-5f) * gamma[c] + beta[c];
  v = v > 0.f ? v : (__expf(v) - 1.f);  // ELU
  g_Fb[i] = f2bf(v);
}

// ---------------- log_softmax over 47 classes ----------------
__global__ void logsm_kernel(const float* __restrict__ X, float* __restrict__ out) {
  int wid = threadIdx.x >> 6, lane = threadIdx.x & 63;
  int n = blockIdx.x * 4 + wid;
  if (n >= NN) return;
  float v = (lane < NCLS) ? X[(size_t)n * NCLS + lane] : -INFINITY;
  float m = v;
#pragma unroll
  for (int o = 32; o > 0; o >>= 1) m = fmaxf(m, __shfl_xor(m, o, 64));
  float ex = (lane < NCLS) ? __expf(v - m) : 0.f;
  float s = wsum(ex);
  if (lane < NCLS) out[(size_t)n * NCLS + lane] = v - m - logf(s);
}

// ---------------- launch ----------------
extern "C" void kernel_launch(void* const* d_in, const int* in_sizes, int n_in,
                              void* d_out, int out_size, void* d_ws, size_t ws_size,
                              hipStream_t stream) {
  const float* x = (const float*)d_in[0];
  const int* ei = (const int*)d_in[1];
  const int* src = ei;
  const int* dst = ei + EE;
  const float* w0 = (const float*)d_in[2];
  const float* as0 = (const float*)d_in[3];
  const float* ad0 = (const float*)d_in[4];
  const float* b0 = (const float*)d_in[5];
  const float* sw0 = (const float*)d_in[6];
  const float* sb0 = (const float*)d_in[7];
  const float* gm0 = (const float*)d_in[8];
  const float* be0 = (const float*)d_in[9];
  const float* w1 = (const float*)d_in[10];
  const float* as1 = (const float*)d_in[11];
  const float* ad1 = (const float*)d_in[12];
  const float* b1 = (const float*)d_in[13];
  const float* sw1 = (const float*)d_in[14];
  const float* sb1 = (const float*)d_in[15];
  const float* gm1 = (const float*)d_in[16];
  const float* be1 = (const float*)d_in[17];
  const float* w2 = (const float*)d_in[18];
  const float* as2 = (const float*)d_in[19];
  const float* ad2 = (const float*)d_in[20];
  const float* b2 = (const float*)d_in[21];
  const float* sw2 = (const float*)d_in[22];
  const float* sb2 = (const float*)d_in[23];
  float* out = (float*)d_out;

  ushortt *Hb, *Fb, *Xb, *Wc0, *Wc1, *Wc2;
  float* Sf;
  hipGetSymbolAddress((void**)&Hb, HIP_SYMBOL(g_Hb));
  hipGetSymbolAddress((void**)&Sf, HIP_SYMBOL(g_Sf));
  hipGetSymbolAddress((void**)&Fb, HIP_SYMBOL(g_Fb));
  hipGetSymbolAddress((void**)&Xb, HIP_SYMBOL(g_Xb));
  hipGetSymbolAddress((void**)&Wc0, HIP_SYMBOL(g_Wc0));
  hipGetSymbolAddress((void**)&Wc1, HIP_SYMBOL(g_Wc1));
  hipGetSymbolAddress((void**)&Wc2, HIP_SYMBOL(g_Wc2));

  // CSR by destination (edge_index constant across layers)
  zero_counts_kernel<<<(NN + 255) / 256, 256, 0, stream>>>();
  count_kernel<<<(EE + 255) / 256, 256, 0, stream>>>(dst);
  scan_kernel<<<1, 1024, 0, stream>>>();
  scatter_kernel<<<(EE + 255) / 256, 256, 0, stream>>>(dst);

  // conversions
  conv_w_kernel<<<(512 * 128 + 512 * 256 + 235 * 256 + 255) / 256, 256, 0, stream>>>(
      w0, sw0, w1, sw1, w2, sw2);
  conv_x_kernel<<<(NN * 128 + 255) / 256, 256, 0, stream>>>(x);

  const int gy = (NN + 63) / 64;  // 469

  // ---- layer 0 ----
  mfma_gemm<<<dim3(8, gy), 256, 0, stream>>>(Xb, Wc0, Hb, Sf, NN, 128, 512, 256, 256, 256, sb0);
  al_kernel<<<(NN + 3) / 4, 256, 0, stream>>>(Hb, as0, ad0, 64);
  attn_kernel<<<NN, 64, 0, stream>>>(Hb, src, b0, Sf);
  zero_stat_kernel<<<2, 256, 0, stream>>>();
  bn_stats_kernel<<<240, 256, 0, stream>>>(Sf);
  bn_norm_kernel<<<(NN * 256 + 255) / 256, 256, 0, stream>>>(Sf, gm0, be0);

  // ---- layer 1 ----
  mfma_gemm<<<dim3(8, gy), 256, 0, stream>>>(Fb, Wc1, Hb, Sf, NN, 256, 512, 256, 256, 256, sb1);
  al_kernel<<<(NN + 3) / 4, 256, 0, stream>>>(Hb, as1, ad1, 64);
  attn_kernel<<<NN, 64, 0, stream>>>(Hb, src, b1, Sf);
  zero_stat_kernel<<<2, 256, 0, stream>>>();
  bn_stats_kernel<<<240, 256, 0, stream>>>(Sf);
  bn_norm_kernel<<<(NN * 256 + 255) / 256, 256, 0, stream>>>(Sf, gm1, be1);

  // ---- layer 2 ----
  mfma_gemm<<<dim3(4, gy), 256, 0, stream>>>(Fb, Wc2, Hb, Sf, NN, 256, 235, 188, 188, 47, sb2);
  al_kernel<<<(NN + 3) / 4, 256, 0, stream>>>(Hb, as2, ad2, NCLS);
  attn2_kernel<<<NN, 64, 0, stream>>>(Hb, src, b2, Sf);
  logsm_kernel<<<(NN + 3) / 4, 256, 0, stream>>>(Sf, out);
}

// Round 4
// 594.430 us; speedup vs baseline: 1.8895x; 1.0805x over previous
//
#include <hip/hip_runtime.h>
#include <math.h>

#define NN 30000
#define EE 480000
#define FIN 100
#define NCLS 47
#define HC2 188     // heads*ncls
#define SCAN_B 118  // ceil(30000/256)

typedef unsigned short ushortt;
typedef __attribute__((ext_vector_type(8))) short bf16x8;
typedef __attribute__((ext_vector_type(4))) float f32x4;

// ---------------- static device workspace ----------------
__device__ ushortt g_Hb[(size_t)NN * 256];   // attention features h, bf16 (layer2: [N,188])
__device__ float   g_Sf[(size_t)NN * 256];   // skip pre-sum fp32, then pre-BN in place
__device__ ushortt g_Fb[(size_t)NN * 256];   // post-BN features bf16 (next GEMM input)
__device__ ushortt g_Xb[(size_t)NN * 128];   // x padded 100->128, bf16
__device__ ushortt g_Wc0[512 * 128];         // [W0 | SW0]^T bf16
__device__ ushortt g_Wc1[512 * 256];         // [W1 | SW1]^T
__device__ ushortt g_Wc2[235 * 256];         // [W2(188) | SW2(47)]^T
__device__ float g_als[NN * 4];
__device__ float g_ald[NN * 4];
__device__ int   g_rowptr[NN + 1];
__device__ int   g_counts[NN];
__device__ int   g_bsum[128];                // per-block sums for scan
__device__ int   g_eids[EE];
__device__ float g_stat[512];                // per-col sum / sumsq

// ---------------- helpers ----------------
__device__ __forceinline__ float wsum(float v) {
#pragma unroll
  for (int o = 32; o > 0; o >>= 1) v += __shfl_xor(v, o, 64);
  return v;
}
__device__ __forceinline__ float lrelu(float x) { return x > 0.f ? x : 0.2f * x; }
__device__ __forceinline__ ushortt f2bf(float f) {
  unsigned int u = __float_as_uint(f);
  unsigned int r = u + 0x7FFF + ((u >> 16) & 1);
  return (ushortt)(r >> 16);
}
__device__ __forceinline__ float bf2f(ushortt u) {
  return __uint_as_float(((unsigned int)u) << 16);
}

// ---------------- CSR build ----------------
__global__ void count_kernel(const int* __restrict__ dst) {
  int e = blockIdx.x * blockDim.x + threadIdx.x;
  if (e < EE) atomicAdd(&g_counts[dst[e]], 1);
}
// stage 1: per-block (256-elem) sums
__global__ void scan1_kernel() {
  int i = blockIdx.x * 256 + threadIdx.x;
  int v = (i < NN) ? g_counts[i] : 0;
  // block reduce: wave-level then LDS
  __shared__ int sh[4];
  float fv = (float)v;
  fv = wsum(fv);
  if ((threadIdx.x & 63) == 0) sh[threadIdx.x >> 6] = (int)fv;
  __syncthreads();
  if (threadIdx.x == 0) g_bsum[blockIdx.x] = sh[0] + sh[1] + sh[2] + sh[3];
}
// stage 2: exclusive scan of SCAN_B block sums (single tiny block)
__global__ void scan2_kernel() {
  __shared__ int sh[128];
  int t = threadIdx.x;
  int v = (t < SCAN_B) ? g_bsum[t] : 0;
  sh[t] = v;
  __syncthreads();
  for (int off = 1; off < 128; off <<= 1) {
    int x = (t >= off) ? sh[t - off] : 0;
    __syncthreads();
    sh[t] += x;
    __syncthreads();
  }
  g_bsum[t] = sh[t] - v;  // exclusive
}
// stage 3: local exclusive scan + block offset -> rowptr; reset counts
__global__ void scan3_kernel() {
  __shared__ int sh[256];
  int t = threadIdx.x;
  int i = blockIdx.x * 256 + t;
  int v = (i < NN) ? g_counts[i] : 0;
  sh[t] = v;
  __syncthreads();
  for (int off = 1; off < 256; off <<= 1) {
    int x = (t >= off) ? sh[t - off] : 0;
    __syncthreads();
    sh[t] += x;
    __syncthreads();
  }
  if (i < NN) {
    g_rowptr[i] = g_bsum[blockIdx.x] + sh[t] - v;
    g_counts[i] = 0;
  }
  if (i == NN - 1) g_rowptr[NN] = EE;
}
__global__ void scatter_kernel(const int* __restrict__ dst) {
  int e = blockIdx.x * blockDim.x + threadIdx.x;
  if (e < EE) {
    int d = dst[e];
    int pos = g_rowptr[d] + atomicAdd(&g_counts[d], 1);
    g_eids[pos] = e;
  }
}

// ---------------- conversions ----------------
__global__ void conv_x_kernel(const float* __restrict__ x) {
  int i = blockIdx.x * blockDim.x + threadIdx.x;
  if (i >= NN * 128) return;
  int r = i >> 7, k = i & 127;
  g_Xb[i] = (k < FIN) ? f2bf(x[r * FIN + k]) : 0;
}
// all weights -> concatenated transposed bf16 buffers
__global__ void conv_w_kernel(const float* __restrict__ w0, const float* __restrict__ sw0,
                              const float* __restrict__ w1, const float* __restrict__ sw1,
                              const float* __restrict__ w2, const float* __restrict__ sw2) {
  int i = blockIdx.x * blockDim.x + threadIdx.x;
  if (i < 512 * 128) {
    int m = i >> 7, k = i & 127;
    float v = 0.f;
    if (k < FIN) v = (m < 256) ? w0[k * 256 + m] : sw0[k * 256 + (m - 256)];
    g_Wc0[i] = f2bf(v);
    return;
  }
  i -= 512 * 128;
  if (i < 512 * 256) {
    int m = i >> 8, k = i & 255;
    float v = (m < 256) ? w1[k * 256 + m] : sw1[k * 256 + (m - 256)];
    g_Wc1[i] = f2bf(v);
    return;
  }
  i -= 512 * 256;
  if (i < 235 * 256) {
    int m = i >> 8, k = i & 255;
    float v = (m < 188) ? w2[(size_t)k * 188 + m] : sw2[(size_t)k * 47 + (m - 188)];
    g_Wc2[i] = f2bf(v);
  }
}

// ---------------- MFMA GEMM with split epilogue ----------------
// A bf16 [nrows,Kp]; Wt bf16 [M][Kp]; cols < S -> out1 bf16 (no bias);
// cols >= S -> out2 fp32 (+bias2).
__global__ __launch_bounds__(256) void mfma_gemm(
    const ushortt* __restrict__ A, const ushortt* __restrict__ Wt,
    ushortt* __restrict__ out1, float* __restrict__ out2,
    int nrows, int Kp, int M, int S, int ld1, int ld2,
    const float* __restrict__ bias2) {
  __shared__ ushortt As[64][40];
  __shared__ ushortt Ws[64][40];
  int t = threadIdx.x;
  int wave = t >> 6, lane = t & 63;
  int row0 = blockIdx.y * 64, col0 = blockIdx.x * 64;
  int lr = t >> 2;
  int lk = (t & 3) * 8;
  int m16 = lane & 15, q = lane >> 4;

  f32x4 acc[4];
#pragma unroll
  for (int i = 0; i < 4; i++) acc[i] = (f32x4){0.f, 0.f, 0.f, 0.f};

  for (int k0 = 0; k0 < Kp; k0 += 32) {
    uint4 av = {0, 0, 0, 0};
    int r = row0 + lr;
    if (r < nrows) av = *(const uint4*)(A + (size_t)r * Kp + k0 + lk);
    *(uint4*)(&As[lr][lk]) = av;
    uint4 wv = {0, 0, 0, 0};
    int c = col0 + lr;
    if (c < M) wv = *(const uint4*)(Wt + (size_t)c * Kp + k0 + lk);
    *(uint4*)(&Ws[lr][lk]) = wv;
    __syncthreads();
    bf16x8 bfrag = *(const bf16x8*)(&Ws[wave * 16 + m16][q * 8]);
#pragma unroll
    for (int rt = 0; rt < 4; rt++) {
      bf16x8 afrag = *(const bf16x8*)(&As[rt * 16 + m16][q * 8]);
      acc[rt] = __builtin_amdgcn_mfma_f32_16x16x32_bf16(afrag, bfrag, acc[rt], 0, 0, 0);
    }
    __syncthreads();
  }
  int c = col0 + wave * 16 + m16;
  if (c < M) {
#pragma unroll
    for (int rt = 0; rt < 4; rt++) {
#pragma unroll
      for (int reg = 0; reg < 4; reg++) {
        int r = row0 + rt * 16 + q * 4 + reg;
        if (r < nrows) {
          float v = acc[rt][reg];
          if (c < S) out1[(size_t)r * ld1 + c] = f2bf(v);
          else out2[(size_t)r * ld2 + (c - S)] = v + bias2[c - S];
        }
      }
    }
  }
}

// ---------------- attention logits per node: al_s/al_d [N,4] (bf16 input) ----------------
__global__ void al_kernel(const ushortt* __restrict__ Hb, const float* __restrict__ a_s,
                          const float* __restrict__ a_d, int C) {
  int wid = threadIdx.x >> 6, lane = threadIdx.x & 63;
  int n = blockIdx.x * 4 + wid;
  if (n >= NN) return;
  int HCl = 4 * C;
  float s0 = 0, s1 = 0, s2 = 0, s3 = 0, d0 = 0, d1 = 0, d2 = 0, d3 = 0;
  if (lane < C) {
    float h0 = bf2f(Hb[(size_t)n * HCl + 0 * C + lane]);
    float h1 = bf2f(Hb[(size_t)n * HCl + 1 * C + lane]);
    float h2 = bf2f(Hb[(size_t)n * HCl + 2 * C + lane]);
    float h3 = bf2f(Hb[(size_t)n * HCl + 3 * C + lane]);
    s0 = h0 * a_s[0 * C + lane]; s1 = h1 * a_s[1 * C + lane];
    s2 = h2 * a_s[2 * C + lane]; s3 = h3 * a_s[3 * C + lane];
    d0 = h0 * a_d[0 * C + lane]; d1 = h1 * a_d[1 * C + lane];
    d2 = h2 * a_d[2 * C + lane]; d3 = h3 * a_d[3 * C + lane];
  }
  s0 = wsum(s0); s1 = wsum(s1); s2 = wsum(s2); s3 = wsum(s3);
  d0 = wsum(d0); d1 = wsum(d1); d2 = wsum(d2); d3 = wsum(d3);
  if (lane == 0) {
    g_als[n * 4 + 0] = s0; g_als[n * 4 + 1] = s1; g_als[n * 4 + 2] = s2; g_als[n * 4 + 3] = s3;
    g_ald[n * 4 + 0] = d0; g_ald[n * 4 + 1] = d1; g_ald[n * 4 + 2] = d2; g_ald[n * 4 + 3] = d3;
  }
}

// ---------------- fused softmax + aggregate + skip-add, C=64 concat ----------------
// No max-subtraction: logits are lrelu of O(1) sums, exp cannot overflow, and
// softmax is shift-invariant. Output written in place over Sf (pre-BN sum).
__global__ __launch_bounds__(64) void attn_kernel(const ushortt* __restrict__ Hb,
                                                  const int* __restrict__ src,
                                                  const float* __restrict__ bias,
                                                  float* __restrict__ Sf) {
  __shared__ __align__(16) float p_sh[64 * 4];
  __shared__ int s_sh[64];
  int n = blockIdx.x, lane = threadIdx.x;
  int rs = g_rowptr[n], deg = g_rowptr[n + 1] - rs;
  float4 ald = *(const float4*)(g_ald + n * 4);
  int q = lane >> 4;
  float den0 = 0, den1 = 0, den2 = 0, den3 = 0;
  float a0 = 0, a1 = 0, a2 = 0, a3 = 0;
  for (int base = 0; base < deg; base += 64) {
    int j = base + lane;
    float p0 = 0, p1 = 0, p2 = 0, p3 = 0;
    int s = 0;
    if (j < deg) {
      int e = g_eids[rs + j];
      s = src[e];
      float4 av = *(const float4*)(g_als + s * 4);
      p0 = __expf(lrelu(av.x + ald.x)); den0 += p0;
      p1 = __expf(lrelu(av.y + ald.y)); den1 += p1;
      p2 = __expf(lrelu(av.z + ald.z)); den2 += p2;
      p3 = __expf(lrelu(av.w + ald.w)); den3 += p3;
    }
    p_sh[lane * 4 + 0] = p0; p_sh[lane * 4 + 1] = p1;
    p_sh[lane * 4 + 2] = p2; p_sh[lane * 4 + 3] = p3;
    s_sh[lane] = s;
    __syncthreads();
    int cnt = min(64, deg - base);
    for (int jj = 0; jj < cnt; jj++) {
      int ss = s_sh[jj];
      float p = p_sh[jj * 4 + q];
      ushort4 hv = *(const ushort4*)(Hb + (size_t)ss * 256 + 4 * lane);
      a0 += p * bf2f(hv.x);
      a1 += p * bf2f(hv.y);
      a2 += p * bf2f(hv.z);
      a3 += p * bf2f(hv.w);
    }
    __syncthreads();
  }
  den0 = wsum(den0); den1 = wsum(den1); den2 = wsum(den2); den3 = wsum(den3);
  float denq = (q == 0) ? den0 : (q == 1) ? den1 : (q == 2) ? den2 : den3;
  float inv = 1.f / (denq + 1e-16f);
  float4 sv = *(const float4*)(Sf + (size_t)n * 256 + 4 * lane);
  float4 bv = *(const float4*)(bias + 4 * lane);
  float4 o;
  o.x = a0 * inv + bv.x + sv.x;
  o.y = a1 * inv + bv.y + sv.y;
  o.z = a2 * inv + bv.z + sv.z;
  o.w = a3 * inv + bv.w + sv.w;
  *(float4*)(Sf + (size_t)n * 256 + 4 * lane) = o;
}

// ---------------- layer-2: softmax + aggregate, mean over heads, +skip ----------------
__global__ __launch_bounds__(64) void attn2_kernel(const ushortt* __restrict__ Hb,
                                                   const int* __restrict__ src,
                                                   const float* __restrict__ bias,
                                                   float* __restrict__ Sf) {
  __shared__ __align__(16) float p_sh[64 * 4];
  __shared__ int s_sh[64];
  int n = blockIdx.x, lane = threadIdx.x;
  int rs = g_rowptr[n], deg = g_rowptr[n + 1] - rs;
  float4 ald = *(const float4*)(g_ald + n * 4);
  float den0 = 0, den1 = 0, den2 = 0, den3 = 0;
  float a0 = 0, a1 = 0, a2 = 0, a3 = 0;
  for (int base = 0; base < deg; base += 64) {
    int j = base + lane;
    float p0 = 0, p1 = 0, p2 = 0, p3 = 0;
    int s = 0;
    if (j < deg) {
      int e = g_eids[rs + j];
      s = src[e];
      float4 av = *(const float4*)(g_als + s * 4);
      p0 = __expf(lrelu(av.x + ald.x)); den0 += p0;
      p1 = __expf(lrelu(av.y + ald.y)); den1 += p1;
      p2 = __expf(lrelu(av.z + ald.z)); den2 += p2;
      p3 = __expf(lrelu(av.w + ald.w)); den3 += p3;
    }
    p_sh[lane * 4 + 0] = p0; p_sh[lane * 4 + 1] = p1;
    p_sh[lane * 4 + 2] = p2; p_sh[lane * 4 + 3] = p3;
    s_sh[lane] = s;
    __syncthreads();
    int cnt = min(64, deg - base);
    for (int jj = 0; jj < cnt; jj++) {
      int ss = s_sh[jj];
      float4 pv = *(const float4*)&p_sh[jj * 4];
      if (lane < NCLS) {
        const ushortt* hr = Hb + (size_t)ss * HC2;
        a0 += pv.x * bf2f(hr[0 * NCLS + lane]);
        a1 += pv.y * bf2f(hr[1 * NCLS + lane]);
        a2 += pv.z * bf2f(hr[2 * NCLS + lane]);
        a3 += pv.w * bf2f(hr[3 * NCLS + lane]);
      }
    }
    __syncthreads();
  }
  den0 = wsum(den0); den1 = wsum(den1); den2 = wsum(den2); den3 = wsum(den3);
  if (lane < NCLS) {
    float v = 0.25f * (a0 / (den0 + 1e-16f) + a1 / (den1 + 1e-16f) +
                       a2 / (den2 + 1e-16f) + a3 / (den3 + 1e-16f));
    Sf[(size_t)n * NCLS + lane] = v + bias[lane] + Sf[(size_t)n * NCLS + lane];
  }
}

// ---------------- BatchNorm ----------------
__global__ void zero_stat_kernel() {
  int i = blockIdx.x * blockDim.x + threadIdx.x;
  if (i < 512) g_stat[i] = 0.f;
}
__global__ void bn_stats_kernel(const float* __restrict__ X) {
  int c = threadIdx.x;  // 256 cols
  int rows = (NN + gridDim.x - 1) / gridDim.x;
  int r0 = blockIdx.x * rows, r1 = min(r0 + rows, NN);
  float s = 0, q = 0;
  for (int r = r0; r < r1; r++) {
    float v = X[(size_t)r * 256 + c];
    s += v;
    q += v * v;
  }
  atomicAdd(&g_stat[c], s);
  atomicAdd(&g_stat[256 + c], q);
}
// normalize + ELU, write bf16 features for next layer's GEMM
__global__ void bn_norm_kernel(const float* __restrict__ X, const float* __restrict__ gamma,
                               const float* __restrict__ beta) {
  int i = blockIdx.x * blockDim.x + threadIdx.x;
  if (i >= NN * 256) return;
  int c = i & 255;
  float mu = g_stat[c] * (1.f / NN);
  float var = g_stat[256 + c] * (1.f / NN) - mu * mu;
  float v = (X[i] - mu) * rsqrtf(var + 1e-5f) * gamma[c] + beta[c];
  v = v > 0.f ? v : (__expf(v) - 1.f);  // ELU
  g_Fb[i] = f2bf(v);
}

// ---------------- log_softmax over 47 classes ----------------
__global__ void logsm_kernel(const float* __restrict__ X, float* __restrict__ out) {
  int wid = threadIdx.x >> 6, lane = threadIdx.x & 63;
  int n = blockIdx.x * 4 + wid;
  if (n >= NN) return;
  float v = (lane < NCLS) ? X[(size_t)n * NCLS + lane] : -INFINITY;
  float m = v;
#pragma unroll
  for (int o = 32; o > 0; o >>= 1) m = fmaxf(m, __shfl_xor(m, o, 64));
  float ex = (lane < NCLS) ? __expf(v - m) : 0.f;
  float s = wsum(ex);
  if (lane < NCLS) out[(size_t)n * NCLS + lane] = v - m - logf(s);
}

// ---------------- launch ----------------
extern "C" void kernel_launch(void* const* d_in, const int* in_sizes, int n_in,
                              void* d_out, int out_size, void* d_ws, size_t ws_size,
                              hipStream_t stream) {
  const float* x = (const float*)d_in[0];
  const int* ei = (const int*)d_in[1];
  const int* src = ei;
  const int* dst = ei + EE;
  const float* w0 = (const float*)d_in[2];
  const float* as0 = (const float*)d_in[3];
  const float* ad0 = (const float*)d_in[4];
  const float* b0 = (const float*)d_in[5];
  const float* sw0 = (const float*)d_in[6];
  const float* sb0 = (const float*)d_in[7];
  const float* gm0 = (const float*)d_in[8];
  const float* be0 = (const float*)d_in[9];
  const float* w1 = (const float*)d_in[10];
  const float* as1 = (const float*)d_in[11];
  const float* ad1 = (const float*)d_in[12];
  const float* b1 = (const float*)d_in[13];
  const float* sw1 = (const float*)d_in[14];
  const float* sb1 = (const float*)d_in[15];
  const float* gm1 = (const float*)d_in[16];
  const float* be1 = (const float*)d_in[17];
  const float* w2 = (const float*)d_in[18];
  const float* as2 = (const float*)d_in[19];
  const float* ad2 = (const float*)d_in[20];
  const float* b2 = (const float*)d_in[21];
  const float* sw2 = (const float*)d_in[22];
  const float* sb2 = (const float*)d_in[23];
  float* out = (float*)d_out;

  ushortt *Hb, *Fb, *Xb, *Wc0, *Wc1, *Wc2;
  float* Sf;
  int* counts;
  hipGetSymbolAddress((void**)&Hb, HIP_SYMBOL(g_Hb));
  hipGetSymbolAddress((void**)&Sf, HIP_SYMBOL(g_Sf));
  hipGetSymbolAddress((void**)&Fb, HIP_SYMBOL(g_Fb));
  hipGetSymbolAddress((void**)&Xb, HIP_SYMBOL(g_Xb));
  hipGetSymbolAddress((void**)&Wc0, HIP_SYMBOL(g_Wc0));
  hipGetSymbolAddress((void**)&Wc1, HIP_SYMBOL(g_Wc1));
  hipGetSymbolAddress((void**)&Wc2, HIP_SYMBOL(g_Wc2));
  hipGetSymbolAddress((void**)&counts, HIP_SYMBOL(g_counts));

  // CSR by destination (edge_index constant across layers)
  hipMemsetAsync(counts, 0, NN * sizeof(int), stream);
  count_kernel<<<(EE + 255) / 256, 256, 0, stream>>>(dst);
  scan1_kernel<<<SCAN_B, 256, 0, stream>>>();
  scan2_kernel<<<1, 128, 0, stream>>>();
  scan3_kernel<<<SCAN_B, 256, 0, stream>>>();
  scatter_kernel<<<(EE + 255) / 256, 256, 0, stream>>>(dst);

  // conversions
  conv_w_kernel<<<(512 * 128 + 512 * 256 + 235 * 256 + 255) / 256, 256, 0, stream>>>(
      w0, sw0, w1, sw1, w2, sw2);
  conv_x_kernel<<<(NN * 128 + 255) / 256, 256, 0, stream>>>(x);

  const int gy = (NN + 63) / 64;  // 469

  // ---- layer 0 ----
  mfma_gemm<<<dim3(8, gy), 256, 0, stream>>>(Xb, Wc0, Hb, Sf, NN, 128, 512, 256, 256, 256, sb0);
  al_kernel<<<(NN + 3) / 4, 256, 0, stream>>>(Hb, as0, ad0, 64);
  attn_kernel<<<NN, 64, 0, stream>>>(Hb, src, b0, Sf);
  zero_stat_kernel<<<2, 256, 0, stream>>>();
  bn_stats_kernel<<<240, 256, 0, stream>>>(Sf);
  bn_norm_kernel<<<(NN * 256 + 255) / 256, 256, 0, stream>>>(Sf, gm0, be0);

  // ---- layer 1 ----
  mfma_gemm<<<dim3(8, gy), 256, 0, stream>>>(Fb, Wc1, Hb, Sf, NN, 256, 512, 256, 256, 256, sb1);
  al_kernel<<<(NN + 3) / 4, 256, 0, stream>>>(Hb, as1, ad1, 64);
  attn_kernel<<<NN, 64, 0, stream>>>(Hb, src, b1, Sf);
  zero_stat_kernel<<<2, 256, 0, stream>>>();
  bn_stats_kernel<<<240, 256, 0, stream>>>(Sf);
  bn_norm_kernel<<<(NN * 256 + 255) / 256, 256, 0, stream>>>(Sf, gm1, be1);

  // ---- layer 2 ----
  mfma_gemm<<<dim3(4, gy), 256, 0, stream>>>(Fb, Wc2, Hb, Sf, NN, 256, 235, 188, 188, 47, sb2);
  al_kernel<<<(NN + 3) / 4, 256, 0, stream>>>(Hb, as2, ad2, NCLS);
  attn2_kernel<<<NN, 64, 0, stream>>>(Hb, src, b2, Sf);
  logsm_kernel<<<(NN + 3) / 4, 256, 0, stream>>>(Sf, out);
}